// Round 7
// baseline (207.038 us; speedup 1.0000x reference)
//
#include <hip/hip_runtime.h>

#define HW 4096
#define CDIM 256
#define BK 32

typedef _Float16 half8 __attribute__((ext_vector_type(8)));
typedef _Float16 half4v __attribute__((ext_vector_type(4)));
typedef float f32x4 __attribute__((ext_vector_type(4)));

__device__ __forceinline__ void top3_ins(float v, float& a0, float& a1, float& a2) {
  float m01 = fminf(a0, v);
  a0 = fmaxf(a0, v);
  float m12 = fminf(a1, m01);
  a1 = fmaxf(a1, m01);
  a2 = fmaxf(a2, m12);
}

__device__ __forceinline__ float mask_val(const float* gtab, int s, int t) {
  int dr = (s >> 6) - (t >> 6); dr = dr < 0 ? -dr : dr;
  int dc = (s & 63) - (t & 63); dc = dc < 0 ? -dc : dc;
  return 1.0f - gtab[dr] * gtab[dc];
}

// upper-triangle linear index -> (i<=j), j in [0,32)  [verified in R2 runs]
__device__ __forceinline__ void tri_map(int L, int& i, int& j) {
  int jj = (int)((sqrtf(8.f * (float)L + 1.f) - 1.f) * 0.5f);
  while ((jj + 1) * (jj + 2) / 2 <= L) ++jj;
  while (jj * (jj + 1) / 2 > L) --jj;
  j = jj;
  i = L - jj * (jj + 1) / 2;
}

__device__ __forceinline__ void async_copy16(const void* g, void* l) {
  __builtin_amdgcn_global_load_lds((const __attribute__((address_space(1))) void*)g,
                                   (__attribute__((address_space(3))) void*)l, 16, 0, 0);
}

// Swizzled LDS staging (proven): slot(lane) = (row=lane>>2, chunk'=lane&3); receives
// GLOBAL chunk c = (chunk' - (row>>1)) & 3 so readers at chunk' = (q + (row>>1)) & 3
// see global chunk q. 2-way LDS aliasing (free).
__device__ __forceinline__ void stage_slice(const _Float16* __restrict__ X,
                                            int rowBase, int k0,
                                            _Float16* sdst, int w, int lane) {
  const int csrc = ((lane & 3) - ((lane >> 3) & 3)) & 3;
#pragma unroll
  for (int i = 0; i < 2; ++i) {
    const int rchunk = w * 32 + i * 16;
    const _Float16* g =
        X + (size_t)(rowBase + rchunk + (lane >> 2)) * CDIM + k0 + csrc * 8;
    async_copy16(g, sdst + rchunk * BK);  // HW appends lane*16B
  }
}

// ---------------- kernel 1: channel-L2 normalize + fp16 transpose ----------------
__global__ void __launch_bounds__(256) normalize_k(const float* __restrict__ x,
                                                   _Float16* __restrict__ Xf) {
  const int p = threadIdx.x & 31;
  const int g = threadIdx.x >> 5;
  const int P0 = blockIdx.x * 32;
  const int b = P0 >> 12;
  const int ph = (P0 & (HW - 1)) + p;
  const float* xb = x + (size_t)b * CDIM * HW + ph;
  float vals[32];
  float ss = 0.f;
#pragma unroll
  for (int k = 0; k < 32; ++k) {
    float v = xb[(size_t)(g * 32 + k) * HW];
    vals[k] = v;
    ss += v * v;
  }
  __shared__ float ssqp[8][33];
  __shared__ float scl[32];
  ssqp[g][p] = ss;
  __syncthreads();
  if (threadIdx.x < 32) {
    float s2 = 0.f;
#pragma unroll
    for (int gg = 0; gg < 8; ++gg) s2 += ssqp[gg][threadIdx.x];
    scl[threadIdx.x] = 1.0f / fmaxf(sqrtf(s2), 1e-12f);
  }
  __syncthreads();
  const float sc = scl[p];
  _Float16* o = Xf + (size_t)(P0 + p) * CDIM + g * 32;
#pragma unroll
  for (int c8 = 0; c8 < 4; ++c8) {
    half8 h;
#pragma unroll
    for (int j = 0; j < 8; ++j) h[j] = (_Float16)(vals[c8 * 8 + j] * sc);
    *(half8*)(o + c8 * 8) = h;
  }
}

// ---- kernel 2: TRIANGULAR GEMM pass -> fp16 e-tiles (normal + mirrored transpose)
// into out_x row prefixes; R via col sums (i<=j) + mirror row sums (i<j).
// E is symmetric: only 528 of 1024 tiles computed; each off-diagonal tile stored
// twice via LDS bounce so both stores are coalesced half8 rows. ----
__global__ void __launch_bounds__(256, 3) gemmE16_k(const _Float16* __restrict__ Xf,
                                                    const float* __restrict__ alphap,
                                                    float* __restrict__ R,
                                                    float* __restrict__ outX) {
  __shared__ _Float16 smem[4][128 * BK];  // mainloop: A/B dbuf; epilogue: 128x128 e-tile
  __shared__ float gtab[64];
  if (threadIdx.x < 64) {
    float d = (float)threadIdx.x;
    gtab[threadIdx.x] = __expf(-d * d * 0.048828125f);
  }
  int iT, jT;
  tri_map(blockIdx.x, iT, jT);
  const int mBase = iT * 128;
  const int nBase = jT * 128;
  const bool offd = (iT != jT);
  const float alpha = alphap[0];
  const int b = blockIdx.z;
  const _Float16* X = Xf + (size_t)b * HW * CDIM;
  const int lane = threadIdx.x & 63;
  const int w = threadIdx.x >> 6;
  const int wr = w >> 1, wc = w & 1;

  f32x4 acc[4][4];
#pragma unroll
  for (int mi = 0; mi < 4; ++mi)
#pragma unroll
    for (int ni = 0; ni < 4; ++ni) acc[mi][ni] = (f32x4){0.f, 0.f, 0.f, 0.f};

  const int aRow0 = wr * 64 + (lane & 15);
  const int bRow0 = wc * 64 + (lane & 15);
  const int cswz = (((lane >> 4) + ((lane >> 1) & 3)) & 3) * 8;

  stage_slice(X, mBase, 0, smem[0], w, lane);
  stage_slice(X, nBase, 0, smem[2], w, lane);

  int cur = 0;
#pragma unroll
  for (int k0 = 0; k0 < CDIM; k0 += BK) {
    __syncthreads();
    if (k0 + BK < CDIM) {
      stage_slice(X, mBase, k0 + BK, smem[cur ^ 1], w, lane);
      stage_slice(X, nBase, k0 + BK, smem[2 + (cur ^ 1)], w, lane);
    }
    half8 a[4], bfr[4];
#pragma unroll
    for (int i = 0; i < 4; ++i)
      a[i] = *(const half8*)(smem[cur] + (aRow0 + 16 * i) * BK + cswz);
#pragma unroll
    for (int i = 0; i < 4; ++i)
      bfr[i] = *(const half8*)(smem[2 + cur] + (bRow0 + 16 * i) * BK + cswz);
#pragma unroll
    for (int mi = 0; mi < 4; ++mi)
#pragma unroll
      for (int ni = 0; ni < 4; ++ni)
        acc[mi][ni] = __builtin_amdgcn_mfma_f32_16x16x32_f16(a[mi], bfr[ni], acc[mi][ni], 0, 0, 0);
    cur ^= 1;
  }

  __syncthreads();  // all LDS reads of staged tiles complete before e-tile overwrite
  _Float16* et = &smem[0][0];  // 16384 halves = full 128x128 swizzled e-tile
  const int quad = lane >> 4;
  float* Rb = R + b * HW;
  half4v esave[4][4];  // e in fp16, kept for the mirror pass (constant indices only)
  float csum[4] = {0.f, 0.f, 0.f, 0.f};
#pragma unroll
  for (int mi = 0; mi < 4; ++mi) {
#pragma unroll
    for (int r = 0; r < 4; ++r) {
      const int row = wr * 64 + mi * 16 + quad * 4 + r;
      const int s = mBase + row;
      const int v = (row >> 2) & 7;
      float rsum = 0.f;
#pragma unroll
      for (int ni = 0; ni < 4; ++ni) {
        const int col = wc * 64 + ni * 16 + (lane & 15);
        const int t = nBase + col;
        float e = __expf(alpha * mask_val(gtab, s, t) * acc[mi][ni][r]);
        csum[ni] += e;
        rsum += e;
        _Float16 eh = (_Float16)e;
        esave[mi][r][ni] = eh;
        et[row * 128 + ((((col >> 4) ^ v) << 4) | (col & 15))] = eh;
      }
      if (offd) {
        // mirror row sum: R[s] += sum over this tile's 128 cols (each 16-group = one row)
#pragma unroll
        for (int off = 1; off < 16; off <<= 1) rsum += __shfl_xor(rsum, off);
        if ((lane & 15) == 0) atomicAdd(&Rb[s], rsum);
      }
    }
  }
  // column sums of unrounded e -> R[t]
#pragma unroll
  for (int off = 16; off < 64; off <<= 1)
#pragma unroll
    for (int ni = 0; ni < 4; ++ni) csum[ni] += __shfl_xor(csum[ni], off);
  if (quad == 0) {
#pragma unroll
    for (int ni = 0; ni < 4; ++ni)
      atomicAdd(&Rb[nBase + wc * 64 + ni * 16 + (lane & 15)], csum[ni]);
  }
  __syncthreads();
  // normal tile store: 16 lanes cover one full 256B row; 4 rows per wave inst
  _Float16* Hb = (_Float16*)(outX + (size_t)b * HW * HW);
  const int c8 = threadIdx.x & 15;   // col chunk of 8 halves
  const int r0 = threadIdx.x >> 4;   // 0..15
#pragma unroll
  for (int pass = 0; pass < 8; ++pass) {
    const int row = pass * 16 + r0;
    const int v = (row >> 2) & 7;
    half8 hv = *(const half8*)(et + row * 128 + ((((c8 >> 1) ^ v) << 4) | ((c8 & 1) * 8)));
    *(half8*)(Hb + (size_t)(mBase + row) * (2 * HW) + nBase + c8 * 8) = hv;
  }
  if (offd) {
    __syncthreads();  // normal-store reads of et done before transpose overwrite
    // rebuild et as the TRANSPOSED tile from registers (roles of row/col swapped)
#pragma unroll
    for (int mi = 0; mi < 4; ++mi) {
#pragma unroll
      for (int r = 0; r < 4; ++r) {
        const int row = wr * 64 + mi * 16 + quad * 4 + r;
#pragma unroll
        for (int ni = 0; ni < 4; ++ni) {
          const int col = wc * 64 + ni * 16 + (lane & 15);
          et[col * 128 + ((((row >> 4) ^ ((col >> 2) & 7)) << 4) | (row & 15))] =
              esave[mi][r][ni];
        }
      }
    }
    __syncthreads();
    // mirror tile store at block (jT, iT): rows = t, cols = s, coalesced half8
#pragma unroll
    for (int pass = 0; pass < 8; ++pass) {
      const int tl = pass * 16 + r0;
      const int v2 = (tl >> 2) & 7;
      half8 hv = *(const half8*)(et + tl * 128 + ((((c8 >> 1) ^ v2) << 4) | ((c8 & 1) * 8)));
      *(half8*)(Hb + (size_t)(nBase + tl) * (2 * HW) + mBase + c8 * 8) = hv;
    }
  }
}

// ---- kernel 3: stream fp16 E -> T[t] partials + per-chunk top3 of g = e^2*invR[s] ----
// grid (4 s-chunks of 1024, 64 t-stripes of 64, b); 16B/lane loads, 32 rows x 8 chunks
__global__ void __launch_bounds__(256) colstats16_k(const float* __restrict__ outX,
                                                    const float* __restrict__ R,
                                                    float* __restrict__ T,
                                                    float* __restrict__ part) {
  const int b = blockIdx.z;
  const _Float16* Hb = (const _Float16*)(outX + (size_t)b * HW * HW);
  const float* Rb = R + b * HW;
  const int s0 = blockIdx.x * 1024;
  const int t0 = blockIdx.y * 64;
  const int tg = threadIdx.x & 7;   // 8 chunks x 8 halves = 64 t
  const int sr = threadIdx.x >> 3;  // 32 rows
  float ts[8], q0[8], q1[8], q2[8];
#pragma unroll
  for (int j = 0; j < 8; ++j) { ts[j] = 0.f; q0[j] = 0.f; q1[j] = 0.f; q2[j] = 0.f; }
#pragma unroll 4
  for (int k = 0; k < 32; ++k) {
    const int s = s0 + k * 32 + sr;
    const float inv = 1.0f / Rb[s];
    half8 ev = *(const half8*)(Hb + (size_t)s * (2 * HW) + t0 + tg * 8);
#pragma unroll
    for (int j = 0; j < 8; ++j) {
      float e = (float)ev[j];
      float gval = e * e * inv;
      ts[j] += gval;
      top3_ins(gval, q0[j], q1[j], q2[j]);
    }
  }
  __shared__ float Tp[32][68], P0a[32][68], P1a[32][68], P2a[32][68];
#pragma unroll
  for (int j = 0; j < 8; ++j) {
    Tp[sr][tg * 8 + j] = ts[j];
    P0a[sr][tg * 8 + j] = q0[j];
    P1a[sr][tg * 8 + j] = q1[j];
    P2a[sr][tg * 8 + j] = q2[j];
  }
  __syncthreads();
  if (threadIdx.x < 64) {
    float tsum = 0.f, a0 = 0.f, a1 = 0.f, a2 = 0.f;
#pragma unroll
    for (int s2 = 0; s2 < 32; ++s2) {
      tsum += Tp[s2][threadIdx.x];
      top3_ins(P0a[s2][threadIdx.x], a0, a1, a2);
      top3_ins(P1a[s2][threadIdx.x], a0, a1, a2);
      top3_ins(P2a[s2][threadIdx.x], a0, a1, a2);
    }
    const int t = t0 + threadIdx.x;
    atomicAdd(&T[b * HW + t], tsum);
    float* pp = part + ((size_t)(b * 4 + blockIdx.x) * HW + t) * 3;
    pp[0] = a0;
    pp[1] = a1;
    pp[2] = a2;
  }
}

// -------- kernel 4: merge 4 top3 partials -> val; W[t] = 1/(T + 1e-8*R) --------
__global__ void __launch_bounds__(256) merge_k(const float* __restrict__ R,
                                               const float* __restrict__ T,
                                               const float* __restrict__ part,
                                               float* __restrict__ W,
                                               float* __restrict__ val_out) {
  const int idx = blockIdx.x * 256 + threadIdx.x;
  const int b = idx >> 12;
  const int t = idx & (HW - 1);
  float a0 = 0.f, a1 = 0.f, a2 = 0.f;
#pragma unroll
  for (int c = 0; c < 4; ++c) {
    const float* pp = part + ((size_t)(b * 4 + c) * HW + t) * 3;
    top3_ins(pp[0], a0, a1, a2);
    top3_ins(pp[1], a0, a1, a2);
    top3_ins(pp[2], a0, a1, a2);
  }
  const float r = R[idx];
  const float invr = 1.0f / r;
  val_out[(b * 3 + 0) * HW + t] = a0 * invr;  // col-sum C_t == R_t by symmetry
  val_out[(b * 3 + 1) * HW + t] = a1 * invr;
  val_out[(b * 3 + 2) * HW + t] = a2 * invr;
  W[idx] = 1.0f / (T[idx] + 1e-8f * r);
}

// ---- kernel 5: x_soft = e^2 * invR[s] * W[t]. Race-free: per row, ALL threads load
// the fp16 prefix into registers, __syncthreads (drains vmcnt block-wide), then store.
// Software-pipelined: row r+1 loads issue after the barrier, overlapping row r stores. ----
#define WROWS 8
__global__ void __launch_bounds__(256) writeout16_k(const float* __restrict__ R,
                                                    const float* __restrict__ W,
                                                    float* __restrict__ X) {
  const int b = blockIdx.y;
  float* Xb = X + (size_t)b * HW * HW;
  const _Float16* Hb = (const _Float16*)Xb;
  const float* Wb = W + b * HW;
  const float* Rb = R + b * HW;
  const int s0 = blockIdx.x * WROWS;
  // W is row-invariant: hoist
  f32x4 wv[4];
#pragma unroll
  for (int it = 0; it < 4; ++it)
    wv[it] = *(const f32x4*)(Wb + it * 1024 + threadIdx.x * 4);
  half4v ehA[4], ehB[4];
#pragma unroll
  for (int it = 0; it < 4; ++it)
    ehA[it] = *(const half4v*)(Hb + (size_t)s0 * (2 * HW) + it * 1024 + threadIdx.x * 4);
#pragma unroll
  for (int row = 0; row < WROWS; ++row) {
    __syncthreads();  // all loads of row `row` (issued pre-barrier) complete block-wide
    if (row + 1 < WROWS) {
      const _Float16* hn = Hb + (size_t)(s0 + row + 1) * (2 * HW);
#pragma unroll
      for (int it = 0; it < 4; ++it) {
        half4v v = *(const half4v*)(hn + it * 1024 + threadIdx.x * 4);
        if (row & 1) ehA[it] = v; else ehB[it] = v;
      }
    }
    const float inv = 1.0f / Rb[s0 + row];
    float* rowp = Xb + (size_t)(s0 + row) * HW;
#pragma unroll
    for (int it = 0; it < 4; ++it) {
      const int t = it * 1024 + threadIdx.x * 4;
      half4v cur = (row & 1) ? ehB[it] : ehA[it];
      f32x4 o;
#pragma unroll
      for (int j = 0; j < 4; ++j) {
        float e = (float)cur[j];
        o[j] = e * e * inv * wv[it][j];
      }
      *(f32x4*)(rowp + t) = o;
    }
  }
}

extern "C" void kernel_launch(void* const* d_in, const int* in_sizes, int n_in,
                              void* d_out, int out_size, void* d_ws, size_t ws_size,
                              hipStream_t stream) {
  const float* x = (const float*)d_in[0];
  const float* alphap = (const float*)d_in[1];
  float* out = (float*)d_out;
  float* out_val = out;                 // (b,3,h,w) = 24576 floats
  float* out_x = out + 2 * 3 * HW;      // (b,hw,h,w): fp16 e-rows first, fp32 x_soft after
  char* ws = (char*)d_ws;

  _Float16* Xf = (_Float16*)ws;                      // 4 MB
  float* R = (float*)(ws + (size_t)4194304);         // 32 KB
  float* T = R + 2 * HW;                             // 32 KB
  float* W = T + 2 * HW;                             // 32 KB
  float* part = W + 2 * HW;                          // 2*4*4096*3*4 = 393 KB

  hipMemsetAsync(R, 0, (size_t)2 * HW * 2 * sizeof(float), stream);  // zero R and T

  normalize_k<<<dim3(256), dim3(256), 0, stream>>>(x, Xf);
  gemmE16_k<<<dim3(528, 1, 2), dim3(256), 0, stream>>>(Xf, alphap, R, out_x);
  colstats16_k<<<dim3(4, 64, 2), dim3(256), 0, stream>>>(out_x, R, T, part);
  merge_k<<<dim3(32), dim3(256), 0, stream>>>(R, T, part, W, out_val);
  writeout16_k<<<dim3(512, 2), dim3(256), 0, stream>>>(R, W, out_x);
}

// Round 8
// 203.336 us; speedup vs baseline: 1.0182x; 1.0182x over previous
//
#include <hip/hip_runtime.h>

#define HW 4096
#define CDIM 256
#define BK 32

typedef _Float16 half8 __attribute__((ext_vector_type(8)));
typedef _Float16 half4v __attribute__((ext_vector_type(4)));
typedef float f32x4 __attribute__((ext_vector_type(4)));

__device__ __forceinline__ void top3_ins(float v, float& a0, float& a1, float& a2) {
  float m01 = fminf(a0, v);
  a0 = fmaxf(a0, v);
  float m12 = fminf(a1, m01);
  a1 = fmaxf(a1, m01);
  a2 = fmaxf(a2, m12);
}

__device__ __forceinline__ float mask_val(const float* gtab, int s, int t) {
  int dr = (s >> 6) - (t >> 6); dr = dr < 0 ? -dr : dr;
  int dc = (s & 63) - (t & 63); dc = dc < 0 ? -dc : dc;
  return 1.0f - gtab[dr] * gtab[dc];
}

__device__ __forceinline__ void async_copy16(const void* g, void* l) {
  __builtin_amdgcn_global_load_lds((const __attribute__((address_space(1))) void*)g,
                                   (__attribute__((address_space(3))) void*)l, 16, 0, 0);
}

// Swizzled LDS staging (proven): slot(lane) = (row=lane>>2, chunk'=lane&3); receives
// GLOBAL chunk c = (chunk' - (row>>1)) & 3 so readers at chunk' = (q + (row>>1)) & 3
// see global chunk q. 2-way LDS aliasing (free).
__device__ __forceinline__ void stage_slice(const _Float16* __restrict__ X,
                                            int rowBase, int k0,
                                            _Float16* sdst, int w, int lane) {
  const int csrc = ((lane & 3) - ((lane >> 3) & 3)) & 3;
#pragma unroll
  for (int i = 0; i < 2; ++i) {
    const int rchunk = w * 32 + i * 16;
    const _Float16* g =
        X + (size_t)(rowBase + rchunk + (lane >> 2)) * CDIM + k0 + csrc * 8;
    async_copy16(g, sdst + rchunk * BK);  // HW appends lane*16B
  }
}

// ---------------- kernel 1: channel-L2 normalize + fp16 transpose ----------------
__global__ void __launch_bounds__(256) normalize_k(const float* __restrict__ x,
                                                   _Float16* __restrict__ Xf) {
  const int p = threadIdx.x & 31;
  const int g = threadIdx.x >> 5;
  const int P0 = blockIdx.x * 32;
  const int b = P0 >> 12;
  const int ph = (P0 & (HW - 1)) + p;
  const float* xb = x + (size_t)b * CDIM * HW + ph;
  float vals[32];
  float ss = 0.f;
#pragma unroll
  for (int k = 0; k < 32; ++k) {
    float v = xb[(size_t)(g * 32 + k) * HW];
    vals[k] = v;
    ss += v * v;
  }
  __shared__ float ssqp[8][33];
  __shared__ float scl[32];
  ssqp[g][p] = ss;
  __syncthreads();
  if (threadIdx.x < 32) {
    float s2 = 0.f;
#pragma unroll
    for (int gg = 0; gg < 8; ++gg) s2 += ssqp[gg][threadIdx.x];
    scl[threadIdx.x] = 1.0f / fmaxf(sqrtf(s2), 1e-12f);
  }
  __syncthreads();
  const float sc = scl[p];
  _Float16* o = Xf + (size_t)(P0 + p) * CDIM + g * 32;
#pragma unroll
  for (int c8 = 0; c8 < 4; ++c8) {
    half8 h;
#pragma unroll
    for (int j = 0; j < 8; ++j) h[j] = (_Float16)(vals[c8 * 8 + j] * sc);
    *(half8*)(o + c8 * 8) = h;
  }
}

// ---- kernel 2: single GEMM pass -> e stored fp16 into out_x row prefixes, R col sums ----
// out_x row s = 4096 f32 (16 KB); its first 8 KB holds the fp16 e-row until writeout
// overwrites it.
__global__ void __launch_bounds__(256, 3) gemmE16_k(const _Float16* __restrict__ Xf,
                                                    const float* __restrict__ alphap,
                                                    float* __restrict__ R,
                                                    float* __restrict__ outX) {
  __shared__ _Float16 sA[2][128 * BK];
  __shared__ _Float16 sB[2][128 * BK];
  __shared__ float gtab[64];
  if (threadIdx.x < 64) {
    float d = (float)threadIdx.x;
    gtab[threadIdx.x] = __expf(-d * d * 0.048828125f);
  }
  const float alpha = alphap[0];
  const int b = blockIdx.z;
  const _Float16* X = Xf + (size_t)b * HW * CDIM;
  const int lane = threadIdx.x & 63;
  const int w = threadIdx.x >> 6;
  const int wr = w >> 1, wc = w & 1;
  const int mBase = blockIdx.y * 128;
  const int nBase = blockIdx.x * 128;

  f32x4 acc[4][4];
#pragma unroll
  for (int mi = 0; mi < 4; ++mi)
#pragma unroll
    for (int ni = 0; ni < 4; ++ni) acc[mi][ni] = (f32x4){0.f, 0.f, 0.f, 0.f};

  const int aRow0 = wr * 64 + (lane & 15);
  const int bRow0 = wc * 64 + (lane & 15);
  const int cswz = (((lane >> 4) + ((lane >> 1) & 3)) & 3) * 8;

  stage_slice(X, mBase, 0, sA[0], w, lane);
  stage_slice(X, nBase, 0, sB[0], w, lane);

  int cur = 0;
#pragma unroll
  for (int k0 = 0; k0 < CDIM; k0 += BK) {
    __syncthreads();
    if (k0 + BK < CDIM) {
      stage_slice(X, mBase, k0 + BK, sA[cur ^ 1], w, lane);
      stage_slice(X, nBase, k0 + BK, sB[cur ^ 1], w, lane);
    }
    half8 a[4], bfr[4];
#pragma unroll
    for (int i = 0; i < 4; ++i)
      a[i] = *(const half8*)(sA[cur] + (aRow0 + 16 * i) * BK + cswz);
#pragma unroll
    for (int i = 0; i < 4; ++i)
      bfr[i] = *(const half8*)(sB[cur] + (bRow0 + 16 * i) * BK + cswz);
#pragma unroll
    for (int mi = 0; mi < 4; ++mi)
#pragma unroll
      for (int ni = 0; ni < 4; ++ni)
        acc[mi][ni] = __builtin_amdgcn_mfma_f32_16x16x32_f16(a[mi], bfr[ni], acc[mi][ni], 0, 0, 0);
    cur ^= 1;
  }

  // epilogue: e = exp(alpha*mask*aff); store fp16 e; column sums (fp32) -> R[t]
  const int quad = lane >> 4;
  _Float16* Hb = (_Float16*)(outX + (size_t)b * HW * HW);
  float csum[4] = {0.f, 0.f, 0.f, 0.f};
#pragma unroll
  for (int mi = 0; mi < 4; ++mi) {
#pragma unroll
    for (int r = 0; r < 4; ++r) {
      const int s = mBase + wr * 64 + mi * 16 + quad * 4 + r;
      _Float16* hrow = Hb + (size_t)s * (2 * HW);
#pragma unroll
      for (int ni = 0; ni < 4; ++ni) {
        const int t = nBase + wc * 64 + ni * 16 + (lane & 15);
        float e = __expf(alpha * mask_val(gtab, s, t) * acc[mi][ni][r]);
        csum[ni] += e;
        hrow[t] = (_Float16)e;
      }
    }
  }
#pragma unroll
  for (int off = 16; off < 64; off <<= 1)
#pragma unroll
    for (int ni = 0; ni < 4; ++ni) csum[ni] += __shfl_xor(csum[ni], off);
  if (quad == 0) {
#pragma unroll
    for (int ni = 0; ni < 4; ++ni)
      atomicAdd(&R[b * HW + nBase + wc * 64 + ni * 16 + (lane & 15)], csum[ni]);
  }
}

// ---- kernel 3: stream fp16 E -> T[t] partials + per-chunk top3 of g = e^2*invR[s] ----
// grid (4 s-chunks of 1024, 64 t-stripes of 64, b)
__global__ void __launch_bounds__(256) colstats16_k(const float* __restrict__ outX,
                                                    const float* __restrict__ R,
                                                    float* __restrict__ T,
                                                    float* __restrict__ part) {
  const int b = blockIdx.z;
  const _Float16* Hb = (const _Float16*)(outX + (size_t)b * HW * HW);
  const float* Rb = R + b * HW;
  const int s0 = blockIdx.x * 1024;
  const int t0 = blockIdx.y * 64;
  const int tg = threadIdx.x & 15;
  const int sr = threadIdx.x >> 4;
  float ts[4] = {0.f, 0.f, 0.f, 0.f};
  float q0[4] = {0.f, 0.f, 0.f, 0.f}, q1[4] = {0.f, 0.f, 0.f, 0.f}, q2[4] = {0.f, 0.f, 0.f, 0.f};
#pragma unroll 4
  for (int k = 0; k < 64; ++k) {
    const int s = s0 + k * 16 + sr;
    const float inv = 1.0f / Rb[s];
    half4v ev = *(const half4v*)(Hb + (size_t)s * (2 * HW) + t0 + tg * 4);
#pragma unroll
    for (int j = 0; j < 4; ++j) {
      float e = (float)ev[j];
      float gval = e * e * inv;
      ts[j] += gval;
      top3_ins(gval, q0[j], q1[j], q2[j]);
    }
  }
  __shared__ float Tp[16][68], P0a[16][68], P1a[16][68], P2a[16][68];
#pragma unroll
  for (int j = 0; j < 4; ++j) {
    Tp[sr][tg * 4 + j] = ts[j];
    P0a[sr][tg * 4 + j] = q0[j];
    P1a[sr][tg * 4 + j] = q1[j];
    P2a[sr][tg * 4 + j] = q2[j];
  }
  __syncthreads();
  if (threadIdx.x < 64) {
    float tsum = 0.f, a0 = 0.f, a1 = 0.f, a2 = 0.f;
#pragma unroll
    for (int s2 = 0; s2 < 16; ++s2) {
      tsum += Tp[s2][threadIdx.x];
      top3_ins(P0a[s2][threadIdx.x], a0, a1, a2);
      top3_ins(P1a[s2][threadIdx.x], a0, a1, a2);
      top3_ins(P2a[s2][threadIdx.x], a0, a1, a2);
    }
    const int t = t0 + threadIdx.x;
    atomicAdd(&T[b * HW + t], tsum);
    float* pp = part + ((size_t)(b * 4 + blockIdx.x) * HW + t) * 3;
    pp[0] = a0;
    pp[1] = a1;
    pp[2] = a2;
  }
}

// -------- kernel 4: merge 4 top3 partials -> val; W[t] = 1/(T + 1e-8*R) --------
__global__ void __launch_bounds__(256) merge_k(const float* __restrict__ R,
                                               const float* __restrict__ T,
                                               const float* __restrict__ part,
                                               float* __restrict__ W,
                                               float* __restrict__ val_out) {
  const int idx = blockIdx.x * 256 + threadIdx.x;
  const int b = idx >> 12;
  const int t = idx & (HW - 1);
  float a0 = 0.f, a1 = 0.f, a2 = 0.f;
#pragma unroll
  for (int c = 0; c < 4; ++c) {
    const float* pp = part + ((size_t)(b * 4 + c) * HW + t) * 3;
    top3_ins(pp[0], a0, a1, a2);
    top3_ins(pp[1], a0, a1, a2);
    top3_ins(pp[2], a0, a1, a2);
  }
  const float r = R[idx];
  const float invr = 1.0f / r;
  val_out[(b * 3 + 0) * HW + t] = a0 * invr;  // col-sum C_t == R_t by symmetry
  val_out[(b * 3 + 1) * HW + t] = a1 * invr;
  val_out[(b * 3 + 2) * HW + t] = a2 * invr;
  W[idx] = 1.0f / (T[idx] + 1e-8f * r);
}

// ---- kernel 5: x_soft = e^2 * invR[s] * W[t]. Race-free: per row, ALL threads load
// the fp16 prefix into registers, __syncthreads (drains vmcnt block-wide), then store.
// Software-pipelined: row r+1 loads issue after the barrier, overlapping row r stores. ----
#define WROWS 8
__global__ void __launch_bounds__(256) writeout16_k(const float* __restrict__ R,
                                                    const float* __restrict__ W,
                                                    float* __restrict__ X) {
  const int b = blockIdx.y;
  float* Xb = X + (size_t)b * HW * HW;
  const _Float16* Hb = (const _Float16*)Xb;
  const float* Wb = W + b * HW;
  const float* Rb = R + b * HW;
  const int s0 = blockIdx.x * WROWS;
  // W is row-invariant: hoist
  f32x4 wv[4];
#pragma unroll
  for (int it = 0; it < 4; ++it)
    wv[it] = *(const f32x4*)(Wb + it * 1024 + threadIdx.x * 4);
  half4v ehA[4], ehB[4];
#pragma unroll
  for (int it = 0; it < 4; ++it)
    ehA[it] = *(const half4v*)(Hb + (size_t)s0 * (2 * HW) + it * 1024 + threadIdx.x * 4);
#pragma unroll
  for (int row = 0; row < WROWS; ++row) {
    __syncthreads();  // all loads of row `row` (issued pre-barrier) complete block-wide
    if (row + 1 < WROWS) {
      const _Float16* hn = Hb + (size_t)(s0 + row + 1) * (2 * HW);
#pragma unroll
      for (int it = 0; it < 4; ++it) {
        half4v v = *(const half4v*)(hn + it * 1024 + threadIdx.x * 4);
        if (row & 1) ehA[it] = v; else ehB[it] = v;
      }
    }
    const float inv = 1.0f / Rb[s0 + row];
    float* rowp = Xb + (size_t)(s0 + row) * HW;
#pragma unroll
    for (int it = 0; it < 4; ++it) {
      const int t = it * 1024 + threadIdx.x * 4;
      half4v cur = (row & 1) ? ehB[it] : ehA[it];
      f32x4 o;
#pragma unroll
      for (int j = 0; j < 4; ++j) {
        float e = (float)cur[j];
        o[j] = e * e * inv * wv[it][j];
      }
      *(f32x4*)(rowp + t) = o;
    }
  }
}

extern "C" void kernel_launch(void* const* d_in, const int* in_sizes, int n_in,
                              void* d_out, int out_size, void* d_ws, size_t ws_size,
                              hipStream_t stream) {
  const float* x = (const float*)d_in[0];
  const float* alphap = (const float*)d_in[1];
  float* out = (float*)d_out;
  float* out_val = out;                 // (b,3,h,w) = 24576 floats
  float* out_x = out + 2 * 3 * HW;      // (b,hw,h,w): fp16 e-rows first, fp32 x_soft after
  char* ws = (char*)d_ws;

  _Float16* Xf = (_Float16*)ws;                      // 4 MB
  float* R = (float*)(ws + (size_t)4194304);         // 32 KB
  float* T = R + 2 * HW;                             // 32 KB
  float* W = T + 2 * HW;                             // 32 KB
  float* part = W + 2 * HW;                          // 2*4*4096*3*4 = 393 KB

  hipMemsetAsync(R, 0, (size_t)2 * HW * 2 * sizeof(float), stream);  // zero R and T

  normalize_k<<<dim3(256), dim3(256), 0, stream>>>(x, Xf);
  gemmE16_k<<<dim3(32, 32, 2), dim3(256), 0, stream>>>(Xf, alphap, R, out_x);
  colstats16_k<<<dim3(4, 64, 2), dim3(256), 0, stream>>>(out_x, R, T, part);
  merge_k<<<dim3(32), dim3(256), 0, stream>>>(R, T, part, W, out_val);
  writeout16_k<<<dim3(512, 2), dim3(256), 0, stream>>>(R, W, out_x);
}